// Round 1
// baseline (1007.799 us; speedup 1.0000x reference)
//
#include <hip/hip_runtime.h>
#include <math.h>

// Problem constants (from setup_inputs)
#define Bb   8
#define Dd   256
#define Tt   500
#define SPK  2000
#define BN   16      // B*N
#define TTILE 32

// ws layout (floats): [0]=dmin_sum, [1]=lse_sum, [8..8+2048) esq, [8+2048..) hsq(8000)
#define WS_ESQ 8
#define WS_HSQ (8 + 2048)
#define WS_FLOATS (8 + 2048 + 8000)

// ---- esq[s] = ||E[s]||^2 : one 64-lane wave per speaker row ----
__global__ void esq_kernel(const float* __restrict__ E, float* __restrict__ ws) {
    int s = blockIdx.x;          // 0..1999
    int lane = threadIdx.x;      // 0..63 : 64 float4 = 256 floats
    const float4* E4 = (const float4*)E;
    float4 v = E4[s * 64 + lane];
    float acc = v.x * v.x + v.y * v.y + v.z * v.z + v.w * v.w;
    #pragma unroll
    for (int off = 32; off > 0; off >>= 1) acc += __shfl_down(acc, off, 64);
    if (lane == 0) ws[WS_ESQ + s] = acc;
}

// ---- hsq[bn,t] = ||H[bn,:,t]||^2 : thread per (bn,t), coalesced over t ----
__global__ void hsq_kernel(const float* __restrict__ H, float* __restrict__ ws) {
    int tid = blockIdx.x * blockDim.x + threadIdx.x;
    if (tid >= BN * Tt) return;
    int bn = tid / Tt, t = tid % Tt;
    const float* Hp = H + (size_t)bn * Dd * Tt + t;
    float acc = 0.f;
    #pragma unroll 8
    for (int d = 0; d < Dd; ++d) { float x = Hp[d * Tt]; acc += x * x; }
    ws[WS_HSQ + tid] = acc;
}

// ---- out[bn*256+d] = E[S[bn,0], d] ----
__global__ void gather_kernel(const float* __restrict__ E, const int* __restrict__ S,
                              float* __restrict__ out) {
    int i = blockIdx.x * blockDim.x + threadIdx.x;  // 0..4095
    int bn = i >> 8, d = i & 255;
    int s = S[bn * Tt];  // t = 0
    out[i] = E[s * Dd + d];
}

// ---- Dmin: thread per (b,t); min over identity/swap alignment ----
__global__ void dmin_kernel(const float* __restrict__ H, const int* __restrict__ S,
                            const float* __restrict__ E, const float* __restrict__ alpha,
                            const float* __restrict__ beta, float* __restrict__ ws) {
    int tid = blockIdx.x * blockDim.x + threadIdx.x;
    float val = 0.f;
    if (tid < Bb * Tt) {
        int b = tid / Tt, t = tid % Tt;
        int s0 = S[(b * 2 + 0) * Tt + t];
        int s1 = S[(b * 2 + 1) * Tt + t];
        const float* h0 = H + ((size_t)(b * 2 + 0) * Dd) * Tt + t;
        const float* h1 = H + ((size_t)(b * 2 + 1) * Dd) * Tt + t;
        const float* e0 = E + (size_t)s0 * Dd;
        const float* e1 = E + (size_t)s1 * Dd;
        float a00 = 0, a01 = 0, a10 = 0, a11 = 0;
        for (int d = 0; d < Dd; ++d) {
            float x0 = h0[(size_t)d * Tt], x1 = h1[(size_t)d * Tt];
            float y0 = e0[d], y1 = e1[d];
            a00 += x0 * y0; a01 += x0 * y1; a10 += x1 * y0; a11 += x1 * y1;
        }
        float hq0 = ws[WS_HSQ + (b * 2 + 0) * Tt + t];
        float hq1 = ws[WS_HSQ + (b * 2 + 1) * Tt + t];
        float eq0 = ws[WS_ESQ + s0];
        float eq1 = ws[WS_ESQ + s1];
        float d00 = hq0 + eq0 - 2.f * a00;   // H0 vs E_S0
        float d11 = hq1 + eq1 - 2.f * a11;   // H1 vs E_S1
        float d01 = hq0 + eq1 - 2.f * a01;   // H0 vs E_S1
        float d10 = hq1 + eq0 - 2.f * a10;   // H1 vs E_S0
        float p0 = d00 + d11, p1 = d01 + d10;
        float dm = fminf(p0, p1);
        val = -alpha[0] * dm + beta[0];
    }
    #pragma unroll
    for (int off = 32; off > 0; off >>= 1) val += __shfl_down(val, off, 64);
    if ((threadIdx.x & 63) == 0) atomicAdd(&ws[0], val);
}

// ---- main fused kernel: per (bn, t-tile) logsumexp over 2000 speakers ----
__global__ __launch_bounds__(256) void lse_kernel(
        const float* __restrict__ H, const float* __restrict__ E,
        const float* __restrict__ alpha, const float* __restrict__ beta,
        float* __restrict__ ws) {
    __shared__ float shH[Dd][TTILE + 1];   // +1 pad: conflict-free both directions
    __shared__ float rm[8][TTILE], rl[8][TTILE];

    int bn = blockIdx.x;                 // 0..15
    int t0 = blockIdx.y * TTILE;         // t-tile base
    int tid = threadIdx.x;
    int tl = tid & 31, sg = tid >> 5;    // t-lane, speaker-group

    // Stage H[bn, :, t0:t0+32] into LDS (thread = one d-row)
    {
        const float* Hp = H + ((size_t)bn * Dd + tid) * Tt;
        #pragma unroll 8
        for (int tt = 0; tt < TTILE; ++tt) {
            int t = t0 + tt;
            shH[tid][tt] = (t < Tt) ? Hp[t] : 0.f;
        }
    }
    __syncthreads();

    int t = t0 + tl;
    float hsqt = (t < Tt) ? ws[WS_HSQ + bn * Tt + t] : 0.f;
    float av = alpha[0], bv = beta[0];
    const float4* E4 = (const float4*)E;

    float m = -INFINITY, l = 0.f;
    for (int base = 0; base < SPK; base += 64) {
        int sbase = base + sg * 8;       // this thread's 8 speakers
        int srow[8];
        #pragma unroll
        for (int j = 0; j < 8; ++j) srow[j] = min(sbase + j, SPK - 1); // clamp OOB loads
        float dot[8] = {0, 0, 0, 0, 0, 0, 0, 0};
        for (int dq = 0; dq < Dd / 4; ++dq) {
            float h0 = shH[dq * 4 + 0][tl];
            float h1 = shH[dq * 4 + 1][tl];
            float h2 = shH[dq * 4 + 2][tl];
            float h3 = shH[dq * 4 + 3][tl];
            #pragma unroll
            for (int j = 0; j < 8; ++j) {
                float4 e = E4[srow[j] * 64 + dq];
                dot[j] += h0 * e.x + h1 * e.y + h2 * e.z + h3 * e.w;
            }
        }
        #pragma unroll
        for (int j = 0; j < 8; ++j) {
            int s = sbase + j;
            if (s < SPK) {
                float v = bv - av * (hsqt + ws[WS_ESQ + s] - 2.f * dot[j]);
                float nm = fmaxf(m, v);
                l = l * __expf(m - nm) + __expf(v - nm);
                m = nm;
            }
        }
    }

    // combine the 8 speaker-groups for each t-lane
    rm[sg][tl] = m; rl[sg][tl] = l;
    __syncthreads();
    if (sg == 0) {
        float M = m;
        #pragma unroll
        for (int g = 1; g < 8; ++g) M = fmaxf(M, rm[g][tl]);
        float L = 0.f;
        #pragma unroll
        for (int g = 0; g < 8; ++g) L += rl[g][tl] * __expf(rm[g][tl] - M);
        float lse = M + __logf(L);
        float val = (t < Tt) ? lse : 0.f;
        #pragma unroll
        for (int off = 16; off > 0; off >>= 1) val += __shfl_down(val, off, 32);
        if (tl == 0) atomicAdd(&ws[1], val);
    }
}

// ---- loss = -mean(Dmin') + mean(lse) ----
__global__ void finalize_kernel(const float* __restrict__ ws, float* __restrict__ out) {
    out[BN * Dd] = -(ws[0] / (float)(Bb * Tt)) + ws[1] / (float)(BN * Tt);
}

extern "C" void kernel_launch(void* const* d_in, const int* in_sizes, int n_in,
                              void* d_out, int out_size, void* d_ws, size_t ws_size,
                              hipStream_t stream) {
    const float* H     = (const float*)d_in[0];
    const int*   S     = (const int*)d_in[1];
    const float* E     = (const float*)d_in[2];
    const float* alpha = (const float*)d_in[3];
    const float* beta  = (const float*)d_in[4];
    float* out = (float*)d_out;
    float* ws  = (float*)d_ws;

    hipMemsetAsync(d_ws, 0, WS_FLOATS * sizeof(float), stream);
    esq_kernel<<<SPK, 64, 0, stream>>>(E, ws);
    hsq_kernel<<<(BN * Tt + 255) / 256, 256, 0, stream>>>(H, ws);
    gather_kernel<<<BN, 256, 0, stream>>>(E, S, out);
    dmin_kernel<<<(Bb * Tt + 255) / 256, 256, 0, stream>>>(H, S, E, alpha, beta, ws);
    lse_kernel<<<dim3(BN, (Tt + TTILE - 1) / TTILE), 256, 0, stream>>>(H, E, alpha, beta, ws);
    finalize_kernel<<<1, 1, 0, stream>>>(ws, out);
}

// Round 2
// 134.407 us; speedup vs baseline: 7.4981x; 7.4981x over previous
//
#include <hip/hip_runtime.h>
#include <math.h>

// Problem constants
#define Bb   8
#define Dd   256
#define Tt   500
#define SPK  2000
#define SPKP 2048     // padded speakers
#define BN   16       // B*N

// ---- ws layout ----
// float indices:
#define F_DMIN 0
#define F_LSE  1
#define F_ESQ  16                  // esq_raw[2048]
#define F_ESN  (F_ESQ + 2048)      // -alpha*esq, pad rows = -1e30  [2048]
#define F_HSQ  (F_ESN + 2048)      // hsq[16*500]
#define F_PM   12288               // partial m [16*512*4]
#define F_PL   (F_PM + 32768)      // partial l [16*512*4]
// byte offset of bf16 E copy:
#define EBF_BYTES ((size_t)(F_PL + 32768) * 4)   // 311296
#define WS_NEED_BYTES (EBF_BYTES + (size_t)SPKP * Dd * 2)  // + 1 MiB

typedef __bf16 v8bf __attribute__((ext_vector_type(8)));
typedef float  v4f  __attribute__((ext_vector_type(4)));

__device__ inline unsigned pack_bf16x2(float lo, float hi) {
    union { __bf16 h; unsigned short u; } a, b;
    a.h = (__bf16)lo; b.h = (__bf16)hi;
    return ((unsigned)b.u << 16) | (unsigned)a.u;
}

// ---- prep_e: E -> bf16 (padded), esq_raw, esn = -alpha*esq ----
__global__ void prep_e_kernel(const float* __restrict__ E, const float* __restrict__ alpha,
                              float* __restrict__ ws) {
    int s = blockIdx.x;          // 0..2047
    int lane = threadIdx.x;      // 0..63
    float4 v = make_float4(0.f, 0.f, 0.f, 0.f);
    if (s < SPK) v = ((const float4*)E)[s * 64 + lane];
    // write bf16 row
    __bf16* ebf = (__bf16*)((char*)ws + EBF_BYTES);
    unsigned2_t: ;
    unsigned p0 = pack_bf16x2(v.x, v.y);
    unsigned p1 = pack_bf16x2(v.z, v.w);
    uint2 pp; pp.x = p0; pp.y = p1;
    *(uint2*)(ebf + (size_t)s * Dd + lane * 4) = pp;
    float acc = v.x * v.x + v.y * v.y + v.z * v.z + v.w * v.w;
    #pragma unroll
    for (int off = 32; off > 0; off >>= 1) acc += __shfl_down(acc, off, 64);
    if (lane == 0) {
        ws[F_ESQ + s] = acc;
        ws[F_ESN + s] = (s < SPK) ? (-alpha[0] * acc) : -1e30f;
    }
}

// ---- hsq[bn,t] = ||H[bn,:,t]||^2 ----
__global__ void hsq_kernel(const float* __restrict__ H, float* __restrict__ ws) {
    int tid = blockIdx.x * blockDim.x + threadIdx.x;
    if (tid >= BN * Tt) return;
    int bn = tid / Tt, t = tid % Tt;
    const float* Hp = H + (size_t)bn * Dd * Tt + t;
    float acc = 0.f;
    #pragma unroll 8
    for (int d = 0; d < Dd; ++d) { float x = Hp[(size_t)d * Tt]; acc += x * x; }
    ws[F_HSQ + tid] = acc;
}

// ---- out[bn*256+d] = E[S[bn,0], d] ----
__global__ void gather_kernel(const float* __restrict__ E, const int* __restrict__ S,
                              float* __restrict__ out) {
    int i = blockIdx.x * blockDim.x + threadIdx.x;  // 0..4095
    int bn = i >> 8, d = i & 255;
    int s = S[bn * Tt];  // t = 0
    out[i] = E[(size_t)s * Dd + d];
}

// ---- Dmin v2: block = (b, t-tile 64), 4 waves split d ----
__global__ __launch_bounds__(256) void dmin2_kernel(
        const float* __restrict__ H, const int* __restrict__ S,
        const float* __restrict__ E, const float* __restrict__ alpha,
        const float* __restrict__ beta, float* __restrict__ ws) {
    __shared__ float4 shm[4][64];
    int b = blockIdx.x;                 // 0..7
    int t0 = blockIdx.y * 64;
    int tl = threadIdx.x & 63;
    int wv = threadIdx.x >> 6;
    int t = t0 + tl;
    bool ok = (t < Tt);
    int tc = ok ? t : (Tt - 1);
    int s0 = S[(b * 2 + 0) * Tt + tc];
    int s1 = S[(b * 2 + 1) * Tt + tc];
    const float* h0 = H + ((size_t)(b * 2 + 0) * Dd) * Tt + tc;
    const float* h1 = H + ((size_t)(b * 2 + 1) * Dd) * Tt + tc;
    const float* e0 = E + (size_t)s0 * Dd;
    const float* e1 = E + (size_t)s1 * Dd;
    float a00 = 0, a01 = 0, a10 = 0, a11 = 0;
    int dbase = wv * 64;
    #pragma unroll 4
    for (int dd = 0; dd < 64; ++dd) {
        int d = dbase + dd;
        float x0 = h0[(size_t)d * Tt], x1 = h1[(size_t)d * Tt];
        float y0 = e0[d], y1 = e1[d];
        a00 = fmaf(x0, y0, a00); a01 = fmaf(x0, y1, a01);
        a10 = fmaf(x1, y0, a10); a11 = fmaf(x1, y1, a11);
    }
    shm[wv][tl] = make_float4(a00, a01, a10, a11);
    __syncthreads();
    if (wv == 0) {
        float4 s0v = shm[0][tl], s1v = shm[1][tl], s2v = shm[2][tl], s3v = shm[3][tl];
        a00 = s0v.x + s1v.x + s2v.x + s3v.x;
        a01 = s0v.y + s1v.y + s2v.y + s3v.y;
        a10 = s0v.z + s1v.z + s2v.z + s3v.z;
        a11 = s0v.w + s1v.w + s2v.w + s3v.w;
        float hq0 = ws[F_HSQ + (b * 2 + 0) * Tt + tc];
        float hq1 = ws[F_HSQ + (b * 2 + 1) * Tt + tc];
        float eq0 = ws[F_ESQ + s0];
        float eq1 = ws[F_ESQ + s1];
        float d00 = hq0 + eq0 - 2.f * a00;
        float d11 = hq1 + eq1 - 2.f * a11;
        float d01 = hq0 + eq1 - 2.f * a01;
        float d10 = hq1 + eq0 - 2.f * a10;
        float dm = fminf(d00 + d11, d01 + d10);
        float val = ok ? (-alpha[0] * dm + beta[0]) : 0.f;
        #pragma unroll
        for (int off = 32; off > 0; off >>= 1) val += __shfl_down(val, off, 64);
        if (tl == 0) atomicAdd(&ws[F_DMIN], val);
    }
}

// ---- main MFMA lse kernel ----
// grid (bn=16, ttile=8 [64 t], schunk=4 [512 spk]), 256 threads = 4 waves (m-split)
__global__ __launch_bounds__(256) void lse_mfma_kernel(
        const float* __restrict__ H, const float* __restrict__ alpha,
        const float* __restrict__ beta, float* __restrict__ ws) {
    __shared__ __bf16 shB[64 * 264];           // [t][k], row 256+8 pad
    __shared__ float mrg_m[4][4][16], mrg_l[4][4][16];

    int bn = blockIdx.x;
    int t0 = blockIdx.y * 64;
    int sc = blockIdx.z;
    int tid = threadIdx.x;
    int lane = tid & 63;
    int n = lane & 15;          // A-row / B-col / C-col lane field
    int q = lane >> 4;          // quad
    int w = tid >> 6;           // wave

    // ---- stage H tile -> LDS bf16 [t][k] ----
    const float* Hb = H + (size_t)bn * Dd * Tt;
    unsigned* shU = (unsigned*)shB;
    #pragma unroll 4
    for (int p = 0; p < 32; ++p) {
        int flat = p * 256 + tid;     // 0..8191
        int kp = flat >> 6;           // k-pair 0..127
        int tt = flat & 63;
        int t = t0 + tt;
        float v0 = 0.f, v1 = 0.f;
        if (t < Tt) {
            v0 = Hb[(size_t)(2 * kp) * Tt + t];
            v1 = Hb[(size_t)(2 * kp + 1) * Tt + t];
        }
        shU[tt * 132 + kp] = pack_bf16x2(v0, v1);
    }
    __syncthreads();

    // ---- B fragments into registers (loop-invariant over speakers) ----
    v8bf bq[4][8];
    #pragma unroll
    for (int i = 0; i < 4; ++i) {
        int tloc = 16 * i + n;
        #pragma unroll
        for (int ks = 0; ks < 8; ++ks) {
            bq[i][ks] = *reinterpret_cast<const v8bf*>(&shB[tloc * 264 + ks * 32 + q * 8]);
        }
    }

    float A = alpha[0], Bv = beta[0];
    float ta2 = 2.f * A;
    float ctc[4];
    #pragma unroll
    for (int i = 0; i < 4; ++i) {
        int t = t0 + 16 * i + n;
        ctc[i] = (t < Tt) ? (Bv - A * ws[F_HSQ + bn * Tt + t]) : 0.f;
    }

    const __bf16* ebf = (const __bf16*)((const char*)ws + EBF_BYTES);
    float lm[4], ll[4];
    #pragma unroll
    for (int i = 0; i < 4; ++i) { lm[i] = -INFINITY; ll[i] = 0.f; }

    for (int step = 0; step < 8; ++step) {
        int sb = sc * 512 + step * 64 + w * 16;   // 16-speaker group base for this wave
        const v8bf* ap = (const v8bf*)(ebf + (size_t)(sb + n) * Dd + q * 8);
        v8bf af[8];
        #pragma unroll
        for (int ks = 0; ks < 8; ++ks) af[ks] = ap[ks * 4];  // stride 32 bf16
        v4f acc[4];
        #pragma unroll
        for (int i = 0; i < 4; ++i) acc[i] = (v4f){0.f, 0.f, 0.f, 0.f};
        #pragma unroll
        for (int ks = 0; ks < 8; ++ks) {
            #pragma unroll
            for (int i = 0; i < 4; ++i) {
                acc[i] = __builtin_amdgcn_mfma_f32_16x16x32_bf16(af[ks], bq[i][ks], acc[i], 0, 0, 0);
            }
        }
        // epilogue: v = ct + esn + 2a*dot, single-exp online lse
        float4 es4 = *(const float4*)(ws + F_ESN + sb + q * 4);
        float esr[4] = {es4.x, es4.y, es4.z, es4.w};
        #pragma unroll
        for (int i = 0; i < 4; ++i) {
            #pragma unroll
            for (int r = 0; r < 4; ++r) {
                float v = fmaf(ta2, acc[i][r], ctc[i] + esr[r]);
                float d = v - lm[i];
                float e = __expf(-fabsf(d));
                if (d > 0.f) { ll[i] = fmaf(ll[i], e, 1.f); lm[i] = v; }
                else         { ll[i] += e; }
            }
        }
    }

    // ---- merge quads within wave (cols repeat every 16 lanes) ----
    #pragma unroll
    for (int i = 0; i < 4; ++i) {
        float m = lm[i], l = ll[i];
        #pragma unroll
        for (int msk = 16; msk <= 32; msk <<= 1) {
            float om = __shfl_xor(m, msk, 64);
            float ol = __shfl_xor(l, msk, 64);
            float nm = fmaxf(m, om);
            l = l * __expf(m - nm) + ol * __expf(om - nm);
            m = nm;
        }
        if (q == 0) { mrg_m[w][i][n] = m; mrg_l[w][i][n] = l; }
    }
    __syncthreads();

    // ---- merge waves, write partials ----
    if (tid < 64) {
        int i = tid >> 4, c = tid & 15;
        float m = mrg_m[0][i][c], l = mrg_l[0][i][c];
        #pragma unroll
        for (int wv = 1; wv < 4; ++wv) {
            float om = mrg_m[wv][i][c], ol = mrg_l[wv][i][c];
            float nm = fmaxf(m, om);
            l = l * __expf(m - nm) + ol * __expf(om - nm);
            m = nm;
        }
        int t = t0 + 16 * i + c;
        if (t < Tt) {
            ws[F_PM + (bn * 512 + t) * 4 + sc] = m;
            ws[F_PL + (bn * 512 + t) * 4 + sc] = l;
        }
    }
}

// ---- combine partial (m,l) over 4 s-chunks, sum lse ----
__global__ void combine_kernel(float* __restrict__ ws) {
    int idx = blockIdx.x * 256 + threadIdx.x;  // 0..8191
    float val = 0.f;
    if (idx < BN * Tt) {
        int bn = idx / Tt, t = idx % Tt;
        int base = (bn * 512 + t) * 4;
        float m = ws[F_PM + base], l = ws[F_PL + base];
        #pragma unroll
        for (int s = 1; s < 4; ++s) {
            float om = ws[F_PM + base + s], ol = ws[F_PL + base + s];
            float nm = fmaxf(m, om);
            l = l * __expf(m - nm) + ol * __expf(om - nm);
            m = nm;
        }
        val = m + logf(l);
    }
    #pragma unroll
    for (int off = 32; off > 0; off >>= 1) val += __shfl_down(val, off, 64);
    if ((threadIdx.x & 63) == 0) atomicAdd(&ws[F_LSE], val);
}

__global__ void finalize_kernel(const float* __restrict__ ws, float* __restrict__ out) {
    out[BN * Dd] = -(ws[F_DMIN] / (float)(Bb * Tt)) + ws[F_LSE] / (float)(BN * Tt);
}

// ================== fallback path (small ws): round-1 fp32 lse ==================
__global__ void esq_old_kernel(const float* __restrict__ E, float* __restrict__ ws) {
    int s = blockIdx.x;
    int lane = threadIdx.x;
    float4 v = ((const float4*)E)[s * 64 + lane];
    float acc = v.x * v.x + v.y * v.y + v.z * v.z + v.w * v.w;
    #pragma unroll
    for (int off = 32; off > 0; off >>= 1) acc += __shfl_down(acc, off, 64);
    if (lane == 0) ws[F_ESQ + s] = acc;
}

__global__ __launch_bounds__(256) void lse_fallback_kernel(
        const float* __restrict__ H, const float* __restrict__ E,
        const float* __restrict__ alpha, const float* __restrict__ beta,
        float* __restrict__ ws) {
    __shared__ float shH[Dd][33];
    __shared__ float rm[8][32], rl[8][32];
    int bn = blockIdx.x;
    int t0 = blockIdx.y * 32;
    int tid = threadIdx.x;
    int tl = tid & 31, sg = tid >> 5;
    {
        const float* Hp = H + ((size_t)bn * Dd + tid) * Tt;
        #pragma unroll 8
        for (int tt = 0; tt < 32; ++tt) {
            int t = t0 + tt;
            shH[tid][tt] = (t < Tt) ? Hp[t] : 0.f;
        }
    }
    __syncthreads();
    int t = t0 + tl;
    float hsqt = (t < Tt) ? ws[F_HSQ + bn * Tt + t] : 0.f;
    float av = alpha[0], bv = beta[0];
    const float4* E4 = (const float4*)E;
    float m = -INFINITY, l = 0.f;
    for (int base = 0; base < SPK; base += 64) {
        int sbase = base + sg * 8;
        float dot[8] = {0, 0, 0, 0, 0, 0, 0, 0};
        for (int dq = 0; dq < Dd / 4; ++dq) {
            float h0 = shH[dq * 4 + 0][tl];
            float h1 = shH[dq * 4 + 1][tl];
            float h2 = shH[dq * 4 + 2][tl];
            float h3 = shH[dq * 4 + 3][tl];
            #pragma unroll
            for (int j = 0; j < 8; ++j) {
                float4 e = E4[(sbase + j) * 64 + dq];
                dot[j] += h0 * e.x + h1 * e.y + h2 * e.z + h3 * e.w;
            }
        }
        #pragma unroll
        for (int j = 0; j < 8; ++j) {
            float v = bv - av * (hsqt + ws[F_ESQ + sbase + j] - 2.f * dot[j]);
            float nm = fmaxf(m, v);
            l = l * __expf(m - nm) + __expf(v - nm);
            m = nm;
        }
    }
    rm[sg][tl] = m; rl[sg][tl] = l;
    __syncthreads();
    if (sg == 0) {
        float M = m;
        #pragma unroll
        for (int g = 1; g < 8; ++g) M = fmaxf(M, rm[g][tl]);
        float L = 0.f;
        #pragma unroll
        for (int g = 0; g < 8; ++g) L += rl[g][tl] * __expf(rm[g][tl] - M);
        float lse = M + __logf(L);
        float val = (t < Tt) ? lse : 0.f;
        #pragma unroll
        for (int off = 16; off > 0; off >>= 1) val += __shfl_down(val, off, 32);
        if (tl == 0) atomicAdd(&ws[F_LSE], val);
    }
}

extern "C" void kernel_launch(void* const* d_in, const int* in_sizes, int n_in,
                              void* d_out, int out_size, void* d_ws, size_t ws_size,
                              hipStream_t stream) {
    const float* H     = (const float*)d_in[0];
    const int*   S     = (const int*)d_in[1];
    const float* E     = (const float*)d_in[2];
    const float* alpha = (const float*)d_in[3];
    const float* beta  = (const float*)d_in[4];
    float* out = (float*)d_out;
    float* ws  = (float*)d_ws;

    hipMemsetAsync(d_ws, 0, 64, stream);
    hsq_kernel<<<(BN * Tt + 255) / 256, 256, 0, stream>>>(H, ws);
    gather_kernel<<<BN, 256, 0, stream>>>(E, S, out);

    if (ws_size >= WS_NEED_BYTES) {
        prep_e_kernel<<<SPKP, 64, 0, stream>>>(E, alpha, ws);
        dmin2_kernel<<<dim3(Bb, 8), 256, 0, stream>>>(H, S, E, alpha, beta, ws);
        lse_mfma_kernel<<<dim3(BN, 8, 4), 256, 0, stream>>>(H, alpha, beta, ws);
        combine_kernel<<<32, 256, 0, stream>>>(ws);
    } else {
        esq_old_kernel<<<SPK, 64, 0, stream>>>(E, ws);
        dmin2_kernel<<<dim3(Bb, 8), 256, 0, stream>>>(H, S, E, alpha, beta, ws);
        lse_fallback_kernel<<<dim3(BN, 16), 256, 0, stream>>>(H, E, alpha, beta, ws);
    }
    finalize_kernel<<<1, 1, 0, stream>>>(ws, out);
}

// Round 3
// 126.839 us; speedup vs baseline: 7.9455x; 1.0597x over previous
//
#include <hip/hip_runtime.h>
#include <math.h>

// Problem constants
#define Bb   8
#define Dd   256
#define Tt   500
#define SPK  2000
#define SPKP 2048     // padded speakers
#define BN   16       // B*N

// ---- ws layout (float indices) ----
#define F_ESN   0                      // -alpha*||E_s||^2, pad rows = -1e30   [2048]
#define F_DMINP 2048                   // per-block dmin partial sums          [64]
#define F_PM    4096                   // partial m [16*512*4]
#define F_PL    (F_PM + 32768)         // partial l [16*512*4]
#define EBF_FLOATS (F_PL + 32768)      // = 69632
#define EBF_BYTES ((size_t)EBF_FLOATS * 4)
#define WS_NEED_BYTES (EBF_BYTES + (size_t)SPKP * Dd * 2)

typedef __bf16 v8bf __attribute__((ext_vector_type(8)));
typedef float  v4f  __attribute__((ext_vector_type(4)));

__device__ inline unsigned pack_bf16x2(float lo, float hi) {
    union { __bf16 h; unsigned short u; } a, b;
    a.h = (__bf16)lo; b.h = (__bf16)hi;
    return ((unsigned)b.u << 16) | (unsigned)a.u;
}

// ================= kernel 1: prep_all =================
// blocks 0..511   : E -> bf16 (4 rows/block) + esn
// blocks 512..527 : gather out[0..4095]
// blocks 528..591 : dmin partials (direct squared-diff, no esq/hsq needed)
__global__ __launch_bounds__(256) void prep_all_kernel(
        const float* __restrict__ E, const int* __restrict__ S,
        const float* __restrict__ H, const float* __restrict__ alpha,
        const float* __restrict__ beta, float* __restrict__ ws,
        float* __restrict__ out) {
    int bid = blockIdx.x;
    int tid = threadIdx.x;

    if (bid < 512) {
        // ---- E -> bf16 + esn ----
        int s = bid * 4 + (tid >> 6);     // 0..2047
        int lane = tid & 63;
        float4 v = make_float4(0.f, 0.f, 0.f, 0.f);
        if (s < SPK) v = ((const float4*)E)[s * 64 + lane];
        __bf16* ebf = (__bf16*)((char*)ws + EBF_BYTES);
        uint2 pp;
        pp.x = pack_bf16x2(v.x, v.y);
        pp.y = pack_bf16x2(v.z, v.w);
        *(uint2*)(ebf + (size_t)s * Dd + lane * 4) = pp;
        float acc = v.x * v.x + v.y * v.y + v.z * v.z + v.w * v.w;
        #pragma unroll
        for (int off = 32; off > 0; off >>= 1) acc += __shfl_down(acc, off, 64);
        if (lane == 0) ws[F_ESN + s] = (s < SPK) ? (-alpha[0] * acc) : -1e30f;
    } else if (bid < 528) {
        // ---- gather: out[i] = E[S[bn,0], d] ----
        int i = (bid - 512) * 256 + tid;  // 0..4095
        int bn = i >> 8, d = i & 255;
        out[i] = E[(size_t)S[bn * Tt] * Dd + d];
    } else {
        // ---- dmin: block q -> (b, t-tile of 64), 4 waves split d ----
        __shared__ float4 shm[4][64];
        int q = bid - 528;                // 0..63
        int b = q >> 3;
        int t0 = (q & 7) * 64;
        int tl = tid & 63;
        int wv = tid >> 6;
        int t = t0 + tl;
        bool ok = (t < Tt);
        int tc = ok ? t : (Tt - 1);
        int s0 = S[(b * 2 + 0) * Tt + tc];
        int s1 = S[(b * 2 + 1) * Tt + tc];
        const float* h0 = H + ((size_t)(b * 2 + 0) * Dd) * Tt + tc;
        const float* h1 = H + ((size_t)(b * 2 + 1) * Dd) * Tt + tc;
        const float* e0 = E + (size_t)s0 * Dd;
        const float* e1 = E + (size_t)s1 * Dd;
        float d00 = 0, d01 = 0, d10 = 0, d11 = 0;
        int dbase = wv * 64;
        #pragma unroll 4
        for (int dd = 0; dd < 64; ++dd) {
            int d = dbase + dd;
            float x0 = h0[(size_t)d * Tt], x1 = h1[(size_t)d * Tt];
            float y0 = e0[d], y1 = e1[d];
            float u;
            u = x0 - y0; d00 = fmaf(u, u, d00);
            u = x0 - y1; d01 = fmaf(u, u, d01);
            u = x1 - y0; d10 = fmaf(u, u, d10);
            u = x1 - y1; d11 = fmaf(u, u, d11);
        }
        shm[wv][tl] = make_float4(d00, d01, d10, d11);
        __syncthreads();
        if (wv == 0) {
            float4 p0 = shm[0][tl], p1 = shm[1][tl], p2 = shm[2][tl], p3 = shm[3][tl];
            d00 = p0.x + p1.x + p2.x + p3.x;
            d01 = p0.y + p1.y + p2.y + p3.y;
            d10 = p0.z + p1.z + p2.z + p3.z;
            d11 = p0.w + p1.w + p2.w + p3.w;
            float dm = fminf(d00 + d11, d01 + d10);
            float val = ok ? (-alpha[0] * dm + beta[0]) : 0.f;
            #pragma unroll
            for (int off = 32; off > 0; off >>= 1) val += __shfl_down(val, off, 64);
            if (tl == 0) ws[F_DMINP + q] = val;
        }
    }
}

// ================= kernel 2: MFMA lse =================
// grid (bn=16, ttile=8 [64 t], schunk=4 [512 spk]), 256 threads = 4 waves (m-split)
__global__ __launch_bounds__(256) void lse_mfma_kernel(
        const float* __restrict__ H, const float* __restrict__ alpha,
        const float* __restrict__ beta, float* __restrict__ ws) {
    __shared__ __bf16 shB[64 * 264];           // [t][k], row 256+8 pad
    __shared__ float mrg_m[4][4][16], mrg_l[4][4][16];
    __shared__ float hsqp[4][64];              // per-w partial ||h_t||^2

    int bn = blockIdx.x;
    int t0 = blockIdx.y * 64;
    int sc = blockIdx.z;
    int tid = threadIdx.x;
    int lane = tid & 63;
    int n = lane & 15;          // A-row / B-col / C-col lane field
    int q = lane >> 4;          // quad
    int w = tid >> 6;           // wave

    // ---- stage H tile -> LDS bf16 [t][k]; fp32 hsq partials on the side ----
    const float* Hb = H + (size_t)bn * Dd * Tt;
    unsigned* shU = (unsigned*)shB;
    float hacc = 0.f;
    #pragma unroll 4
    for (int p = 0; p < 32; ++p) {
        int flat = p * 256 + tid;     // 0..8191
        int kp = flat >> 6;           // k-pair 0..127  (= p*4 + w)
        int tt = flat & 63;           // (= tid & 63)
        int t = t0 + tt;
        float v0 = 0.f, v1 = 0.f;
        if (t < Tt) {
            v0 = Hb[(size_t)(2 * kp) * Tt + t];
            v1 = Hb[(size_t)(2 * kp + 1) * Tt + t];
        }
        hacc = fmaf(v0, v0, hacc);
        hacc = fmaf(v1, v1, hacc);
        shU[tt * 132 + kp] = pack_bf16x2(v0, v1);
    }
    hsqp[w][tid & 63] = hacc;
    __syncthreads();

    // ---- B fragments into registers (loop-invariant over speakers) ----
    v8bf bq[4][8];
    #pragma unroll
    for (int i = 0; i < 4; ++i) {
        int tloc = 16 * i + n;
        #pragma unroll
        for (int ks = 0; ks < 8; ++ks) {
            bq[i][ks] = *reinterpret_cast<const v8bf*>(&shB[tloc * 264 + ks * 32 + q * 8]);
        }
    }

    float A = alpha[0], Bv = beta[0];
    float ta2 = 2.f * A;
    float ctc[4];
    #pragma unroll
    for (int i = 0; i < 4; ++i) {
        int t = t0 + 16 * i + n;
        float hs = hsqp[0][16 * i + n] + hsqp[1][16 * i + n]
                 + hsqp[2][16 * i + n] + hsqp[3][16 * i + n];
        ctc[i] = (t < Tt) ? (Bv - A * hs) : 0.f;
    }

    const __bf16* ebf = (const __bf16*)((const char*)ws + EBF_BYTES);
    float lm[4], ll[4];
    #pragma unroll
    for (int i = 0; i < 4; ++i) { lm[i] = -INFINITY; ll[i] = 0.f; }

    for (int step = 0; step < 8; ++step) {
        int sb = sc * 512 + step * 64 + w * 16;   // 16-speaker base for this wave
        const v8bf* ap = (const v8bf*)(ebf + (size_t)(sb + n) * Dd + q * 8);
        v8bf af[8];
        #pragma unroll
        for (int ks = 0; ks < 8; ++ks) af[ks] = ap[ks * 4];  // stride 32 bf16
        v4f acc[4];
        #pragma unroll
        for (int i = 0; i < 4; ++i) acc[i] = (v4f){0.f, 0.f, 0.f, 0.f};
        #pragma unroll
        for (int ks = 0; ks < 8; ++ks) {
            #pragma unroll
            for (int i = 0; i < 4; ++i) {
                acc[i] = __builtin_amdgcn_mfma_f32_16x16x32_bf16(af[ks], bq[i][ks], acc[i], 0, 0, 0);
            }
        }
        // epilogue: v = ct + esn + 2a*dot, single-exp online lse
        float4 es4 = *(const float4*)(ws + F_ESN + sb + q * 4);
        float esr[4] = {es4.x, es4.y, es4.z, es4.w};
        #pragma unroll
        for (int i = 0; i < 4; ++i) {
            #pragma unroll
            for (int r = 0; r < 4; ++r) {
                float v = fmaf(ta2, acc[i][r], ctc[i] + esr[r]);
                float d = v - lm[i];
                float e = __expf(-fabsf(d));
                if (d > 0.f) { ll[i] = fmaf(ll[i], e, 1.f); lm[i] = v; }
                else         { ll[i] += e; }
            }
        }
    }

    // ---- merge quads within wave (cols repeat every 16 lanes) ----
    #pragma unroll
    for (int i = 0; i < 4; ++i) {
        float m = lm[i], l = ll[i];
        #pragma unroll
        for (int msk = 16; msk <= 32; msk <<= 1) {
            float om = __shfl_xor(m, msk, 64);
            float ol = __shfl_xor(l, msk, 64);
            float nm = fmaxf(m, om);
            l = l * __expf(m - nm) + ol * __expf(om - nm);
            m = nm;
        }
        if (q == 0) { mrg_m[w][i][n] = m; mrg_l[w][i][n] = l; }
    }
    __syncthreads();

    // ---- merge waves, write partials ----
    if (tid < 64) {
        int i = tid >> 4, c = tid & 15;
        float m = mrg_m[0][i][c], l = mrg_l[0][i][c];
        #pragma unroll
        for (int wv = 1; wv < 4; ++wv) {
            float om = mrg_m[wv][i][c], ol = mrg_l[wv][i][c];
            float nm = fmaxf(m, om);
            l = l * __expf(m - nm) + ol * __expf(om - nm);
            m = nm;
        }
        int t = t0 + 16 * i + c;
        if (t < Tt) {
            ws[F_PM + (bn * 512 + t) * 4 + sc] = m;
            ws[F_PL + (bn * 512 + t) * 4 + sc] = l;
        }
    }
}

// ================= kernel 3: final combine =================
// single block: merge s-chunk partials -> lse sum; sum dmin partials; write loss
__global__ __launch_bounds__(256) void final_kernel(const float* __restrict__ ws,
                                                    float* __restrict__ out) {
    __shared__ float rL[4], rD[4];
    int tid = threadIdx.x;
    float lsum = 0.f;
    for (int idx = tid; idx < BN * 512; idx += 256) {
        int bn = idx >> 9, t = idx & 511;
        if (t < Tt) {
            int base = (bn * 512 + t) * 4;
            float m = ws[F_PM + base], l = ws[F_PL + base];
            #pragma unroll
            for (int s = 1; s < 4; ++s) {
                float om = ws[F_PM + base + s], ol = ws[F_PL + base + s];
                float nm = fmaxf(m, om);
                l = l * __expf(m - nm) + ol * __expf(om - nm);
                m = nm;
            }
            lsum += m + __logf(l);
        }
    }
    float dsum = (tid < 64) ? ws[F_DMINP + tid] : 0.f;
    #pragma unroll
    for (int off = 32; off > 0; off >>= 1) {
        lsum += __shfl_down(lsum, off, 64);
        dsum += __shfl_down(dsum, off, 64);
    }
    if ((tid & 63) == 0) { rL[tid >> 6] = lsum; rD[tid >> 6] = dsum; }
    __syncthreads();
    if (tid == 0) {
        float L = rL[0] + rL[1] + rL[2] + rL[3];
        float D = rD[0] + rD[1] + rD[2] + rD[3];
        out[BN * Dd] = -(D / (float)(Bb * Tt)) + L / (float)(BN * Tt);
    }
}

extern "C" void kernel_launch(void* const* d_in, const int* in_sizes, int n_in,
                              void* d_out, int out_size, void* d_ws, size_t ws_size,
                              hipStream_t stream) {
    const float* H     = (const float*)d_in[0];
    const int*   S     = (const int*)d_in[1];
    const float* E     = (const float*)d_in[2];
    const float* alpha = (const float*)d_in[3];
    const float* beta  = (const float*)d_in[4];
    float* out = (float*)d_out;
    float* ws  = (float*)d_ws;

    prep_all_kernel<<<592, 256, 0, stream>>>(E, S, H, alpha, beta, ws, out);
    lse_mfma_kernel<<<dim3(BN, 8, 4), 256, 0, stream>>>(H, alpha, beta, ws);
    final_kernel<<<1, 256, 0, stream>>>(ws, out);
}